// Round 14
// baseline (344.839 us; speedup 1.0000x reference)
//
#include <hip/hip_runtime.h>
#include <math.h>

#define NCH 192
#define NB 8
#define SPAT 32768                        // 32^3
#define POSB 128                          // positions per block (4 W-rows)
#define TILES_PER_B (SPAT / POSB)         // 256
#define NBLK (NB * TILES_PER_B)           // 2048 blocks per pass
#define NELEM_PER_B ((size_t)NCH * SPAT)  // 6291456

typedef short s16x8 __attribute__((ext_vector_type(8)));
typedef float f32x4 __attribute__((ext_vector_type(4)));

__device__ __forceinline__ float bf2f(unsigned short h) {
  return __uint_as_float(((unsigned)h) << 16);
}
__device__ __forceinline__ unsigned short f2bf(float f) {
  unsigned u = __float_as_uint(f);
  u += 0x7FFF + ((u >> 16) & 1);
  return (unsigned short)(u >> 16);
}
__device__ __forceinline__ unsigned cvt_pk(float lo, float hi) {
  unsigned r;
  asm("v_cvt_pk_bf16_f32 %0, %1, %2" : "=v"(r) : "v"(lo), "v"(hi));
  return r;
}

// tanh-form GELU (abs err ~5e-4; budget 9.1e-2)
__device__ __forceinline__ float gelu_f(float x) {
  float x2 = x * x;
  float z2 = x * fmaf(x2, 0.0713548163f, 1.5957769100f);
  float e = __expf(z2);
  float r = __builtin_amdgcn_rcpf(e + 1.0f);
  return fmaf(-r, x, x);
}

// reflect-shift of axis index i by chunk c (s=c-1): -1->1, 32->30
__device__ __forceinline__ int rshift(int i, int c) {
  int j = i - (c - 1);
  j = (j < 0) ? 1 : j;
  j = (j > 31) ? 30 : j;
  return j;
}

// LDS tile [c:3][p:128][u:64] bf16 (128B rows, 48KB); 16B-granule XOR swizzle.
// SINGLE helper for every LDS access (rule #21).
__device__ __forceinline__ int lds_off(int c, int p, int u) {
  return (c * POSB + p) * 128 + 16 * (((u >> 3) ^ (p & 7) ^ ((p >> 3) & 7)) & 7) + 2 * (u & 7);
}

// 48-out-ch x 64-pos GEMM slice, 2-deep pipelined weight fragments (R9 recipe).
//   chb: out-channel block 0..3 (x48); pbase: position half 0/64.
template <int SHIFTW>
__device__ __forceinline__ void do_gemm48(const char* __restrict__ B,
                                          const unsigned short* __restrict__ wm,
                                          int chb, int pbase, int col, int kg,
                                          f32x4 acc[3][4]) {
  const unsigned short* wp = wm + (chb * 48 + col) * NCH + kg * 8;
  s16x8 afc[3], afn[3];
#pragma unroll
  for (int r = 0; r < 3; ++r) afc[r] = *(const s16x8*)(wp + r * 16 * NCH);
#pragma unroll
  for (int ks = 0; ks < 6; ++ks) {
    if (ks < 5) {
#pragma unroll
      for (int r = 0; r < 3; ++r)
        afn[r] = *(const s16x8*)(wp + (ks + 1) * 32 + r * 16 * NCH);
    }
    int k0 = ks * 32 + kg * 8;
    int c = k0 >> 6, u = k0 & 63;
    s16x8 bf[4];
#pragma unroll
    for (int m = 0; m < 4; ++m) {
      int p = pbase + m * 16 + col;
      int ps = SHIFTW ? ((p & ~31) | rshift(p & 31, c)) : p;
      bf[m] = *(const s16x8*)(B + lds_off(c, ps, u));
    }
#pragma unroll
    for (int r = 0; r < 3; ++r)
#pragma unroll
      for (int m = 0; m < 4; ++m)
        acc[r][m] = __builtin_amdgcn_mfma_f32_16x16x32_bf16(afc[r], bf[m], acc[r][m], 0, 0, 0);
#pragma unroll
    for (int r = 0; r < 3; ++r) afc[r] = afn[r];
  }
}

// ---- 512-thread tile staging / storing (6 granules per thread, 48KB) ----
template <int AX>
__device__ __forceinline__ void stage_load8(const char* __restrict__ ib, int p0, int tid,
                                            s16x8 vr[6]) {
#pragma unroll
  for (int j = 0; j < 6; ++j) {
    int g = j * 512 + tid;
    int p = g / 24, r24 = g - 24 * p;
    int c = r24 >> 3;
    int pp = p0 + p, sp = pp;
    if (AX == 3) { int h = (pp >> 5) & 31; sp = pp + (rshift(h, c) - h) * 32; }
    if (AX == 2) { int d = pp >> 10;       sp = pp + (rshift(d, c) - d) * 1024; }
    vr[j] = *(const s16x8*)(ib + (size_t)sp * 384 + r24 * 16);
  }
}

template <int FUSE>
__device__ __forceinline__ void stage_write8(char* __restrict__ B, int tid, const s16x8 vr[6],
                                             const unsigned short* __restrict__ acb) {
#pragma unroll
  for (int j = 0; j < 6; ++j) {
    int g = j * 512 + tid;
    int p = g / 24, r24 = g - 24 * p;
    int c = r24 >> 3, gr = r24 & 7;
    if (FUSE) {
      int ch0 = r24 * 8;
      s16x8 aA = *(const s16x8*)(acb + ch0);
      s16x8 aC = *(const s16x8*)(acb + NCH + ch0);
      unsigned w[4];
#pragma unroll
      for (int i = 0; i < 4; ++i) {
        float f0 = gelu_f(fmaf(bf2f((unsigned short)vr[j][2 * i]),
                               bf2f((unsigned short)aA[2 * i]),
                               bf2f((unsigned short)aC[2 * i])));
        float f1 = gelu_f(fmaf(bf2f((unsigned short)vr[j][2 * i + 1]),
                               bf2f((unsigned short)aA[2 * i + 1]),
                               bf2f((unsigned short)aC[2 * i + 1])));
        w[i] = cvt_pk(f0, f1);
      }
      *(uint2*)(B + lds_off(c, p, gr * 8)) = make_uint2(w[0], w[1]);
      *(uint2*)(B + lds_off(c, p, gr * 8 + 4)) = make_uint2(w[2], w[3]);
    } else {
      *(s16x8*)(B + lds_off(c, p, gr * 8)) = vr[j];
    }
  }
}

__device__ __forceinline__ void store_tile8(const char* __restrict__ L, char* __restrict__ ob,
                                            int tid) {
#pragma unroll
  for (int j = 0; j < 6; ++j) {
    int g = j * 512 + tid;
    int p = g / 24, r24 = g - 24 * p;
    s16x8 v = *(const s16x8*)(L + lds_off(r24 >> 3, p, (r24 & 7) * 8));
    *(s16x8*)(ob + (size_t)g * 16) = v;
  }
}

__device__ __forceinline__ void stats_reduce8(float ssum, float ssq, int wave, int lane,
                                              float* red, float* partials, int blk) {
#pragma unroll
  for (int off = 1; off < 64; off <<= 1) {
    ssum += __shfl_xor(ssum, off, 64);
    ssq += __shfl_xor(ssq, off, 64);
  }
  if (lane == 0) { red[wave * 2] = ssum; red[wave * 2 + 1] = ssq; }
  __syncthreads();
  if (wave == 0 && lane == 0) {
    float a = 0.f, c = 0.f;
#pragma unroll
    for (int w = 0; w < 8; ++w) { a += red[w * 2]; c += red[w * 2 + 1]; }
    partials[blk * 2] = a;
    partials[blk * 2 + 1] = c;
  }
}

// ---------------------------------------------------------------------------
// pass1: x (f32 ch-major) -> conv(w1)+b1 -> bf16 [p][c], stats1.  128-pos.
// ---------------------------------------------------------------------------
__global__ __launch_bounds__(512, 4)
void pass1(const float* __restrict__ x, const unsigned short* __restrict__ w1b,
           const float* __restrict__ b1, unsigned short* __restrict__ out,
           float* __restrict__ partials) {
  __shared__ __align__(16) char B[3 * POSB * 128];   // 48 KB
  __shared__ float red[16];
  int blk = blockIdx.x, b = blk >> 8, p0 = (blk & 255) * POSB;
  int tid = threadIdx.x, wave = tid >> 6, lane = tid & 63;
  int col = lane & 15, kg = lane >> 4;
  int chb = wave & 3, pbase = (wave >> 2) * 64;

  // stage: f32 transpose-gather of ch-pairs, packed b32 writes
  const float* xb = x + (size_t)b * NELEM_PER_B + p0;
  int q = tid & 31;                       // pos-quad 0..31 (128 pos / 4)
#pragma unroll
  for (int j = 0; j < 6; ++j) {
    int chp = j * 16 + (tid >> 5);        // ch-pair 0..95
    int ch0 = 2 * chp;
    int cc = chp >> 5, u0 = ch0 & 63;
    const float* s0 = xb + (size_t)ch0 * SPAT + 4 * q;
    f32x4 a = *(const f32x4*)s0;
    f32x4 c2 = *(const f32x4*)(s0 + SPAT);
#pragma unroll
    for (int i = 0; i < 4; ++i)
      *(unsigned*)(B + lds_off(cc, 4 * q + i, u0)) = cvt_pk(a[i], c2[i]);
  }
  __syncthreads();

  f32x4 acc[3][4] = {};
  do_gemm48<0>(B, w1b, chb, pbase, col, kg, acc);

  float ssum = 0.f, ssq = 0.f;
  __syncthreads();   // all B reads done; reuse as output tile
#pragma unroll
  for (int r = 0; r < 3; ++r) {
    int rowb = chb * 48 + r * 16 + kg * 4;
    f32x4 bs = *(const f32x4*)(b1 + rowb);
#pragma unroll
    for (int m = 0; m < 4; ++m) {
      int p = pbase + m * 16 + col;
      float v0 = acc[r][m][0] + bs[0], v1 = acc[r][m][1] + bs[1];
      float v2 = acc[r][m][2] + bs[2], v3 = acc[r][m][3] + bs[3];
      ssum += (v0 + v1) + (v2 + v3);
      ssq = fmaf(v0, v0, fmaf(v1, v1, fmaf(v2, v2, fmaf(v3, v3, ssq))));
      uint2 pk; pk.x = cvt_pk(v0, v1); pk.y = cvt_pk(v2, v3);
      *(uint2*)(B + lds_off(rowb >> 6, p, rowb & 63)) = pk;
    }
  }
  __syncthreads();
  store_tile8(B, (char*)out + ((size_t)b * SPAT + p0) * 384, tid);
  stats_reduce8(ssum, ssq, wave, lane, red, partials, blk);
}

// ---------------------------------------------------------------------------
// pass2a: H-shift gather + fused norm1-affine+GELU, conv(w22)+b22 -> bf16
// ---------------------------------------------------------------------------
__global__ __launch_bounds__(512, 4)
void pass2a(const unsigned short* __restrict__ in, const unsigned short* __restrict__ w22b,
            const float* __restrict__ b22, unsigned short* __restrict__ out,
            const unsigned short* __restrict__ ACbf) {
  __shared__ __align__(16) char B[3 * POSB * 128];
  int blk = blockIdx.x, b = blk >> 8, p0 = (blk & 255) * POSB;
  int tid = threadIdx.x, wave = tid >> 6, lane = tid & 63;
  int col = lane & 15, kg = lane >> 4;
  int chb = wave & 3, pbase = (wave >> 2) * 64;

  const char* ib = (const char*)in + (size_t)b * SPAT * 384;
  const unsigned short* acb = ACbf + b * 2 * NCH;

  s16x8 vr[6];
  stage_load8<3>(ib, p0, tid, vr);
  stage_write8<1>(B, tid, vr, acb);
  __syncthreads();

  f32x4 acc[3][4] = {};
  do_gemm48<0>(B, w22b, chb, pbase, col, kg, acc);
  __syncthreads();
#pragma unroll
  for (int r = 0; r < 3; ++r) {
    int rowb = chb * 48 + r * 16 + kg * 4;
    f32x4 bs = *(const f32x4*)(b22 + rowb);
#pragma unroll
    for (int m = 0; m < 4; ++m) {
      int p = pbase + m * 16 + col;
      uint2 pk;
      pk.x = cvt_pk(acc[r][m][0] + bs[0], acc[r][m][1] + bs[1]);
      pk.y = cvt_pk(acc[r][m][2] + bs[2], acc[r][m][3] + bs[3]);
      *(uint2*)(B + lds_off(rowb >> 6, p, rowb & 63)) = pk;
    }
  }
  __syncthreads();
  store_tile8(B, (char*)out + ((size_t)b * SPAT + p0) * 384, tid);
}

// ---------------------------------------------------------------------------
// pass2bc: D-shift gather -> conv(w21)+b21 -> T (in-place) -> W-shift read ->
//          conv(w23)+b23 -> GELU -> stats2 -> bf16 [p][c]
// ---------------------------------------------------------------------------
__global__ __launch_bounds__(512, 4)
void pass2bc(const unsigned short* __restrict__ in, const unsigned short* __restrict__ w21b,
             const float* __restrict__ b21, const unsigned short* __restrict__ w23b,
             const float* __restrict__ b23, unsigned short* __restrict__ out,
             float* __restrict__ partials) {
  __shared__ __align__(16) char B[3 * POSB * 128];
  __shared__ float red[16];
  int blk = blockIdx.x, b = blk >> 8, p0 = (blk & 255) * POSB;
  int tid = threadIdx.x, wave = tid >> 6, lane = tid & 63;
  int col = lane & 15, kg = lane >> 4;
  int chb = wave & 3, pbase = (wave >> 2) * 64;

  const char* ib = (const char*)in + (size_t)b * SPAT * 384;

  s16x8 vr[6];
  stage_load8<2>(ib, p0, tid, vr);
  stage_write8<0>(B, tid, vr, nullptr);
  __syncthreads();

  f32x4 acc[3][4] = {};
  do_gemm48<0>(B, w21b, chb, pbase, col, kg, acc);
  __syncthreads();
#pragma unroll
  for (int r = 0; r < 3; ++r) {
    int rowb = chb * 48 + r * 16 + kg * 4;
    f32x4 bs = *(const f32x4*)(b21 + rowb);
#pragma unroll
    for (int m = 0; m < 4; ++m) {
      int p = pbase + m * 16 + col;
      uint2 pk;
      pk.x = cvt_pk(acc[r][m][0] + bs[0], acc[r][m][1] + bs[1]);
      pk.y = cvt_pk(acc[r][m][2] + bs[2], acc[r][m][3] + bs[3]);
      *(uint2*)(B + lds_off(rowb >> 6, p, rowb & 63)) = pk;
    }
  }
  __syncthreads();

#pragma unroll
  for (int r = 0; r < 3; ++r)
#pragma unroll
    for (int m = 0; m < 4; ++m) acc[r][m] = (f32x4){0.f, 0.f, 0.f, 0.f};
  do_gemm48<1>(B, w23b, chb, pbase, col, kg, acc);   // W-shift at read
  __syncthreads();

  float ssum = 0.f, ssq = 0.f;
#pragma unroll
  for (int r = 0; r < 3; ++r) {
    int rowb = chb * 48 + r * 16 + kg * 4;
    f32x4 bs = *(const f32x4*)(b23 + rowb);
#pragma unroll
    for (int m = 0; m < 4; ++m) {
      int p = pbase + m * 16 + col;
      float v0 = gelu_f(acc[r][m][0] + bs[0]), v1 = gelu_f(acc[r][m][1] + bs[1]);
      float v2 = gelu_f(acc[r][m][2] + bs[2]), v3 = gelu_f(acc[r][m][3] + bs[3]);
      ssum += (v0 + v1) + (v2 + v3);
      ssq = fmaf(v0, v0, fmaf(v1, v1, fmaf(v2, v2, fmaf(v3, v3, ssq))));
      uint2 pk; pk.x = cvt_pk(v0, v1); pk.y = cvt_pk(v2, v3);
      *(uint2*)(B + lds_off(rowb >> 6, p, rowb & 63)) = pk;
    }
  }
  __syncthreads();
  store_tile8(B, (char*)out + ((size_t)b * SPAT + p0) * 384, tid);
  stats_reduce8(ssum, ssq, wave, lane, red, partials, blk);
}

// ---------------------------------------------------------------------------
// pass3: conv(w3e per-sample folded norm2)+b3e -> f32 channel-major d_out
// ---------------------------------------------------------------------------
__global__ __launch_bounds__(512, 4)
void pass3(const unsigned short* __restrict__ in, const unsigned short* __restrict__ w3e,
           const float* __restrict__ b3e, float* __restrict__ outf) {
  __shared__ __align__(16) char B[3 * POSB * 128];
  int blk = blockIdx.x, b = blk >> 8, p0 = (blk & 255) * POSB;
  int tid = threadIdx.x, wave = tid >> 6, lane = tid & 63;
  int col = lane & 15, kg = lane >> 4;
  int chb = wave & 3, pbase = (wave >> 2) * 64;

  const char* ib = (const char*)in + (size_t)b * SPAT * 384;

  s16x8 vr[6];
  stage_load8<0>(ib, p0, tid, vr);
  stage_write8<0>(B, tid, vr, nullptr);
  __syncthreads();

  f32x4 acc[3][4] = {};
  do_gemm48<0>(B, w3e + (size_t)b * NCH * NCH, chb, pbase, col, kg, acc);

  const float* bb = b3e + b * NCH;
#pragma unroll
  for (int r = 0; r < 3; ++r) {
    int rowb = chb * 48 + r * 16 + kg * 4;
    f32x4 bs = *(const f32x4*)(bb + rowb);
#pragma unroll
    for (int m = 0; m < 4; ++m) {
      int p = p0 + pbase + m * 16 + col;
#pragma unroll
      for (int j = 0; j < 4; ++j)
        outf[((size_t)b * NCH + rowb + j) * SPAT + p] = acc[r][m][j] + bs[j];
    }
  }
}

// Deterministic stats finalize: nper partials/sample -> f32 AC + bf16 ACbf
__global__ void stats_finalize(const float* __restrict__ partials,
                               const float* __restrict__ nw, const float* __restrict__ nb,
                               float* __restrict__ AC, unsigned short* __restrict__ ACbf,
                               int nper) {
  int b = blockIdx.x, tid = threadIdx.x;
  __shared__ float s0[256], s1[256];
  float a = 0.f, c = 0.f;
  for (int i = tid; i < nper; i += 256) {
    a += partials[(b * nper + i) * 2];
    c += partials[(b * nper + i) * 2 + 1];
  }
  s0[tid] = a; s1[tid] = c;
  __syncthreads();
  for (int st = 128; st > 0; st >>= 1) {
    if (tid < st) { s0[tid] += s0[tid + st]; s1[tid] += s1[tid + st]; }
    __syncthreads();
  }
  float inv_n = 1.0f / (float)NELEM_PER_B;
  float mu = s0[0] * inv_n;
  float var = s1[0] * inv_n - mu * mu;
  float rs = rsqrtf(var + 1e-5f);
  if (tid < NCH) {
    float A = rs * nw[tid];
    float C = nb[tid] - mu * A;
    AC[b * 2 * NCH + tid] = A;
    AC[b * 2 * NCH + NCH + tid] = C;
    ACbf[b * 2 * NCH + tid] = f2bf(A);
    ACbf[b * 2 * NCH + NCH + tid] = f2bf(C);
  }
}

__global__ void prep_weights(const float* __restrict__ w1, const float* __restrict__ w21,
                             const float* __restrict__ w22, const float* __restrict__ w23,
                             unsigned short* __restrict__ wb) {
  int i = blockIdx.x * 256 + threadIdx.x;
  if (i >= 4 * NCH * NCH) return;
  int m = i / (NCH * NCH), r = i % (NCH * NCH);
  const float* src = (m == 0) ? w1 : (m == 1) ? w22 : (m == 2) ? w21 : w23;
  wb[i] = f2bf(src[r]);
}

// Parallel fold of norm2 into w3/b3: one 64-thread block per (b, o)
__global__ void prep_w3p(const float* __restrict__ w3, const float* __restrict__ b3,
                         const float* __restrict__ AC2,
                         unsigned short* __restrict__ w3e, float* __restrict__ b3e) {
  int gb = blockIdx.x;
  int b = gb / NCH, o = gb - b * NCH;
  const float* A = AC2 + b * 2 * NCH;
  const float* C = A + NCH;
  int lane = threadIdx.x;
  float s = 0.f;
#pragma unroll
  for (int k = 0; k < 3; ++k) {
    int c = k * 64 + lane;
    float w = w3[o * NCH + c];
    w3e[((size_t)b * NCH + o) * NCH + c] = f2bf(w * A[c]);
    s = fmaf(w, C[c], s);
  }
#pragma unroll
  for (int off = 1; off < 64; off <<= 1) s += __shfl_xor(s, off, 64);
  if (lane == 0) b3e[b * NCH + o] = b3[o] + s;
}

extern "C" void kernel_launch(void* const* d_in, const int* in_sizes, int n_in,
                              void* d_out, int out_size, void* d_ws, size_t ws_size,
                              hipStream_t stream) {
  const float* x   = (const float*)d_in[0];
  const float* w1  = (const float*)d_in[1];
  const float* b1  = (const float*)d_in[2];
  const float* n1w = (const float*)d_in[3];
  const float* n1b = (const float*)d_in[4];
  const float* w21 = (const float*)d_in[5];
  const float* b21 = (const float*)d_in[6];
  const float* w22 = (const float*)d_in[7];
  const float* b22 = (const float*)d_in[8];
  const float* w23 = (const float*)d_in[9];
  const float* b23 = (const float*)d_in[10];
  const float* n2w = (const float*)d_in[11];
  const float* n2b = (const float*)d_in[12];
  const float* w3  = (const float*)d_in[13];
  const float* b3  = (const float*)d_in[14];

  char* ws = (char*)d_ws;
  size_t off = 0;
  unsigned short* wb = (unsigned short*)(ws + off); off += (size_t)4 * NCH * NCH * 2;
  off = (off + 255) & ~(size_t)255;
  unsigned short* w3e = (unsigned short*)(ws + off); off += (size_t)NB * NCH * NCH * 2;
  off = (off + 255) & ~(size_t)255;
  float* b3e = (float*)(ws + off); off += NB * NCH * 4;
  float* AC1 = (float*)(ws + off); off += NB * 2 * NCH * 4;
  float* AC2 = (float*)(ws + off); off += NB * 2 * NCH * 4;
  unsigned short* ACbf1 = (unsigned short*)(ws + off); off += NB * 2 * NCH * 2;
  unsigned short* ACbf2 = (unsigned short*)(ws + off); off += NB * 2 * NCH * 2;
  off = (off + 255) & ~(size_t)255;
  float* part1 = (float*)(ws + off); off += (size_t)NBLK * 2 * 4;
  float* part2 = (float*)(ws + off); off += (size_t)NBLK * 2 * 4;
  off = (off + 255) & ~(size_t)255;
  unsigned short* R1 = (unsigned short*)(ws + off);   // 100.7 MB bf16 (ws)
  unsigned short* R2 = (unsigned short*)d_out;        // bf16 scratch in d_out

  prep_weights<<<(4 * NCH * NCH + 255) / 256, 256, 0, stream>>>(w1, w21, w22, w23, wb);

  // K1: x -> R1 (conv w1 + b1), stats1
  pass1<<<NBLK, 512, 0, stream>>>(x, wb + 0 * NCH * NCH, b1, R1, part1);
  stats_finalize<<<NB, 256, 0, stream>>>(part1, n1w, n1b, AC1, ACbf1, TILES_PER_B);

  // K2a: H-shift + fused norm1+gelu staging, conv w22: R1 -> R2
  pass2a<<<NBLK, 512, 0, stream>>>(R1, wb + 1 * NCH * NCH, b22, R2, ACbf1);

  // K2bc: D-shift stage -> w21 -> T -> W-shift -> w23 (+gelu+stats2): R2 -> R1
  pass2bc<<<NBLK, 512, 0, stream>>>(R2, wb + 2 * NCH * NCH, b21,
                                    wb + 3 * NCH * NCH, b23, R1, part2);
  stats_finalize<<<NB, 256, 0, stream>>>(part2, n2w, n2b, AC2, ACbf2, TILES_PER_B);
  prep_w3p<<<NB * NCH, 64, 0, stream>>>(w3, b3, AC2, w3e, b3e);

  // K3: folded norm2 + conv w3: R1 -> d_out (f32 channel-major)
  pass3<<<NBLK, 512, 0, stream>>>(R1, w3e, b3e, (float*)d_out);
}

// Round 15
// 320.431 us; speedup vs baseline: 1.0762x; 1.0762x over previous
//
#include <hip/hip_runtime.h>
#include <math.h>

#define NCH 192
#define NB 8
#define SPAT 32768                        // 32^3
#define TILES_PER_B 512                   // 64-pos tiles per sample
#define NBLK (NB * TILES_PER_B)           // 4096 blocks per pass
#define NELEM_PER_B ((size_t)NCH * SPAT)  // 6291456

typedef short s16x8 __attribute__((ext_vector_type(8)));
typedef float f32x4 __attribute__((ext_vector_type(4)));

__device__ __forceinline__ float bf2f(unsigned short h) {
  return __uint_as_float(((unsigned)h) << 16);
}
__device__ __forceinline__ unsigned short f2bf(float f) {
  unsigned u = __float_as_uint(f);
  u += 0x7FFF + ((u >> 16) & 1);
  return (unsigned short)(u >> 16);
}
// packed RNE f32->bf16 pair in ONE instruction
__device__ __forceinline__ unsigned cvt_pk(float lo, float hi) {
  unsigned r;
  asm("v_cvt_pk_bf16_f32 %0, %1, %2" : "=v"(r) : "v"(lo), "v"(hi));
  return r;
}

// tanh-form GELU (max abs err ~5e-4; budget 9.1e-2).  ~8 VALU ops.
__device__ __forceinline__ float gelu_f(float x) {
  float x2 = x * x;
  float z2 = x * fmaf(x2, 0.0713548163f, 1.5957769100f);
  float e = __expf(z2);
  float r = __builtin_amdgcn_rcpf(e + 1.0f);
  return fmaf(-r, x, x);
}

// reflect-shift of axis index i by chunk c (shift s = c-1): -1->1, 32->30
__device__ __forceinline__ int rshift(int i, int c) {
  int j = i - (c - 1);
  j = (j < 0) ? 1 : j;
  j = (j > 31) ? 30 : j;
  return j;
}

// LDS tile [c:3][p:64][u:64] bf16 (128B rows); 16B-granule XOR swizzle
// granule' = (u>>3) ^ (p&7) ^ ((p>>3)&7).  SINGLE helper everywhere (rule #21).
__device__ __forceinline__ int lds_off(int c, int p, int u) {
  return (c * 64 + p) * 128 + 16 * (((u >> 3) ^ (p & 7) ^ ((p >> 3) & 7)) & 7) + 2 * (u & 7);
}

// 48-out-ch-per-wave x 64-pos GEMM with 2-DEEP PIPELINED weight fragments:
// af loads for ks+1 are issued before the MFMAs of ks, so the L2 latency of
// the weight reads is covered by the MFMA+ds_read work of the previous step
// (counted vmcnt, never a full drain).  SHIFTW: W-axis reflect-shift at read.
template <int SHIFTW>
__device__ __forceinline__ void do_gemm48(const char* __restrict__ B,
                                          const unsigned short* __restrict__ wm,
                                          int wave, int col, int kg,
                                          f32x4 acc[3][4]) {
  const unsigned short* wp = wm + (wave * 48 + col) * NCH + kg * 8;
  s16x8 afc[3], afn[3];
#pragma unroll
  for (int r = 0; r < 3; ++r) afc[r] = *(const s16x8*)(wp + r * 16 * NCH);
#pragma unroll
  for (int ks = 0; ks < 6; ++ks) {
    if (ks < 5) {
#pragma unroll
      for (int r = 0; r < 3; ++r)
        afn[r] = *(const s16x8*)(wp + (ks + 1) * 32 + r * 16 * NCH);
    }
    int k0 = ks * 32 + kg * 8;
    int c = k0 >> 6, u = k0 & 63;
    s16x8 bf[4];
#pragma unroll
    for (int m = 0; m < 4; ++m) {
      int p = m * 16 + col;
      int ps = SHIFTW ? ((p & 32) | rshift(p & 31, c)) : p;
      bf[m] = *(const s16x8*)(B + lds_off(c, ps, u));
    }
#pragma unroll
    for (int r = 0; r < 3; ++r)
#pragma unroll
      for (int m = 0; m < 4; ++m)
        acc[r][m] = __builtin_amdgcn_mfma_f32_16x16x32_bf16(afc[r], bf[m], acc[r][m], 0, 0, 0);
#pragma unroll
    for (int r = 0; r < 3; ++r) afc[r] = afn[r];
  }
}

// block (4-wave) stats reduce -> partials[blk]
__device__ __forceinline__ void stats_reduce(float ssum, float ssq, int wave, int lane,
                                             float* red, float* partials, int blk) {
#pragma unroll
  for (int off = 1; off < 64; off <<= 1) {
    ssum += __shfl_xor(ssum, off, 64);
    ssq += __shfl_xor(ssq, off, 64);
  }
  if (lane == 0) { red[wave * 2] = ssum; red[wave * 2 + 1] = ssq; }
  __syncthreads();
  if (wave == 0 && lane == 0) {
    partials[blk * 2] = red[0] + red[2] + red[4] + red[6];
    partials[blk * 2 + 1] = red[1] + red[3] + red[5] + red[7];
  }
}

// coop store: LDS tile -> bf16 [p][c] global (contiguous 24KB)
__device__ __forceinline__ void store_tile(const char* __restrict__ L, char* __restrict__ ob,
                                           int tid) {
  int G = tid & 7;
#pragma unroll
  for (int j = 0; j < 6; ++j) {
    const int c = j >> 1;
    int p = (j & 1) * 32 + (tid >> 3);
    s16x8 v = *(const s16x8*)(L + lds_off(c, p, G * 8));
    *(s16x8*)(ob + (size_t)p * 384 + (c * 8 + G) * 16) = v;
  }
}

// ---------------------------------------------------------------------------
// pass1: x (f32 ch-major) -> conv(w1)+b1 -> bf16 [p][c], stats1
// ---------------------------------------------------------------------------
__global__ __launch_bounds__(256, 4)
void pass1(const float* __restrict__ x, const unsigned short* __restrict__ w1b,
           const float* __restrict__ b1, unsigned short* __restrict__ out,
           float* __restrict__ partials) {
  __shared__ __align__(16) char B[3 * 64 * 128];
  __shared__ float red[8];
  int blk = blockIdx.x, b = blk >> 9, p0 = (blk & 511) * 64;
  int tid = threadIdx.x, wave = tid >> 6, lane = tid & 63;
  int col = lane & 15, kg = lane >> 4;

  // stage: f32 transpose-gather of ch-pairs, packed b32 writes
  const float* xb = x + (size_t)b * NELEM_PER_B + p0;
  int q = tid & 15;
#pragma unroll
  for (int j = 0; j < 6; ++j) {
    int chp = j * 16 + (tid >> 4);          // ch-pair 0..95
    int ch0 = 2 * chp;
    int cc = chp >> 5, u0 = ch0 & 63;
    const float* s0 = xb + (size_t)ch0 * SPAT + 4 * q;
    f32x4 a = *(const f32x4*)s0;
    f32x4 c2 = *(const f32x4*)(s0 + SPAT);
#pragma unroll
    for (int i = 0; i < 4; ++i)
      *(unsigned*)(B + lds_off(cc, 4 * q + i, u0)) = cvt_pk(a[i], c2[i]);
  }
  __syncthreads();

  f32x4 acc[3][4] = {};
  do_gemm48<0>(B, w1b, wave, col, kg, acc);

  float ssum = 0.f, ssq = 0.f;
  __syncthreads();   // all B reads done; reuse as output tile
#pragma unroll
  for (int r = 0; r < 3; ++r) {
    int rowb = wave * 48 + r * 16 + kg * 4;
    f32x4 bs = *(const f32x4*)(b1 + rowb);
#pragma unroll
    for (int m = 0; m < 4; ++m) {
      int p = m * 16 + col;
      float v0 = acc[r][m][0] + bs[0], v1 = acc[r][m][1] + bs[1];
      float v2 = acc[r][m][2] + bs[2], v3 = acc[r][m][3] + bs[3];
      ssum += (v0 + v1) + (v2 + v3);
      ssq = fmaf(v0, v0, fmaf(v1, v1, fmaf(v2, v2, fmaf(v3, v3, ssq))));
      uint2 pk; pk.x = cvt_pk(v0, v1); pk.y = cvt_pk(v2, v3);
      *(uint2*)(B + lds_off(rowb >> 6, p, rowb & 63)) = pk;
    }
  }
  __syncthreads();
  store_tile(B, (char*)out + ((size_t)b * SPAT + p0) * 384, tid);
  stats_reduce(ssum, ssq, wave, lane, red, partials, blk);
}

// ---------------------------------------------------------------------------
// pass2a: H-shift gather + fused norm1-affine+GELU, conv(w22)+b22 -> bf16
// ---------------------------------------------------------------------------
__global__ __launch_bounds__(256, 4)
void pass2a(const unsigned short* __restrict__ in, const unsigned short* __restrict__ w22b,
            const float* __restrict__ b22, unsigned short* __restrict__ out,
            const unsigned short* __restrict__ ACbf) {
  __shared__ __align__(16) char B[3 * 64 * 128];
  int blk = blockIdx.x, b = blk >> 9, p0 = (blk & 511) * 64;
  int tid = threadIdx.x, wave = tid >> 6, lane = tid & 63;
  int col = lane & 15, kg = lane >> 4;

  const char* ib = (const char*)in + (size_t)b * SPAT * 384;
  const unsigned short* acb = ACbf + b * 2 * NCH;
  int G = tid & 7;
#pragma unroll
  for (int j = 0; j < 6; ++j) {
    const int c = j >> 1;
    int p = (j & 1) * 32 + (tid >> 3);
    int h = ((p0 + p) >> 5) & 31;
    int sp = (p0 + p) + (rshift(h, c) - h) * 32;
    s16x8 v = *(const s16x8*)(ib + (size_t)sp * 384 + (c * 8 + G) * 16);
    s16x8 aA = *(const s16x8*)(acb + c * 64 + G * 8);
    s16x8 aC = *(const s16x8*)(acb + NCH + c * 64 + G * 8);
    unsigned w[4];
#pragma unroll
    for (int i = 0; i < 4; ++i) {
      float f0 = gelu_f(fmaf(bf2f((unsigned short)v[2 * i]), bf2f((unsigned short)aA[2 * i]),
                             bf2f((unsigned short)aC[2 * i])));
      float f1 = gelu_f(fmaf(bf2f((unsigned short)v[2 * i + 1]), bf2f((unsigned short)aA[2 * i + 1]),
                             bf2f((unsigned short)aC[2 * i + 1])));
      w[i] = cvt_pk(f0, f1);
    }
    *(uint2*)(B + lds_off(c, p, G * 8)) = make_uint2(w[0], w[1]);
    *(uint2*)(B + lds_off(c, p, G * 8 + 4)) = make_uint2(w[2], w[3]);
  }
  __syncthreads();

  f32x4 acc[3][4] = {};
  do_gemm48<0>(B, w22b, wave, col, kg, acc);
  __syncthreads();
#pragma unroll
  for (int r = 0; r < 3; ++r) {
    int rowb = wave * 48 + r * 16 + kg * 4;
    f32x4 bs = *(const f32x4*)(b22 + rowb);
#pragma unroll
    for (int m = 0; m < 4; ++m) {
      int p = m * 16 + col;
      uint2 pk;
      pk.x = cvt_pk(acc[r][m][0] + bs[0], acc[r][m][1] + bs[1]);
      pk.y = cvt_pk(acc[r][m][2] + bs[2], acc[r][m][3] + bs[3]);
      *(uint2*)(B + lds_off(rowb >> 6, p, rowb & 63)) = pk;
    }
  }
  __syncthreads();
  store_tile(B, (char*)out + ((size_t)b * SPAT + p0) * 384, tid);
}

// ---------------------------------------------------------------------------
// pass2bc: D-shift gather -> conv(w21)+b21 -> T (in-place LDS) -> W-shift
//          read -> conv(w23)+b23 -> GELU -> stats2 -> bf16 [p][c]
// ---------------------------------------------------------------------------
__global__ __launch_bounds__(256, 4)
void pass2bc(const unsigned short* __restrict__ in, const unsigned short* __restrict__ w21b,
             const float* __restrict__ b21, const unsigned short* __restrict__ w23b,
             const float* __restrict__ b23, unsigned short* __restrict__ out,
             float* __restrict__ partials) {
  __shared__ __align__(16) char B[3 * 64 * 128];
  __shared__ float red[8];
  int blk = blockIdx.x, b = blk >> 9, p0 = (blk & 511) * 64;
  int tid = threadIdx.x, wave = tid >> 6, lane = tid & 63;
  int col = lane & 15, kg = lane >> 4;

  int d = p0 >> 10;
  int soff[3];
#pragma unroll
  for (int c = 0; c < 3; ++c) soff[c] = (rshift(d, c) - d) * 1024;

  const char* ib = (const char*)in + (size_t)b * SPAT * 384;
  int G = tid & 7;
#pragma unroll
  for (int j = 0; j < 6; ++j) {
    const int c = j >> 1;
    int p = (j & 1) * 32 + (tid >> 3);
    s16x8 v = *(const s16x8*)(ib + (size_t)(p0 + p + soff[c]) * 384 + (c * 8 + G) * 16);
    *(s16x8*)(B + lds_off(c, p, G * 8)) = v;
  }
  __syncthreads();                         // B visible

  f32x4 acc[3][4] = {};
  do_gemm48<0>(B, w21b, wave, col, kg, acc);
  __syncthreads();                         // GEMM1 reads done
#pragma unroll
  for (int r = 0; r < 3; ++r) {
    int rowb = wave * 48 + r * 16 + kg * 4;
    f32x4 bs = *(const f32x4*)(b21 + rowb);
#pragma unroll
    for (int m = 0; m < 4; ++m) {
      int p = m * 16 + col;
      uint2 pk;
      pk.x = cvt_pk(acc[r][m][0] + bs[0], acc[r][m][1] + bs[1]);
      pk.y = cvt_pk(acc[r][m][2] + bs[2], acc[r][m][3] + bs[3]);
      *(uint2*)(B + lds_off(rowb >> 6, p, rowb & 63)) = pk;
    }
  }
  __syncthreads();                         // T visible

#pragma unroll
  for (int r = 0; r < 3; ++r)
#pragma unroll
    for (int m = 0; m < 4; ++m) acc[r][m] = (f32x4){0.f, 0.f, 0.f, 0.f};
  do_gemm48<1>(B, w23b, wave, col, kg, acc);   // W-shift at read
  __syncthreads();                         // GEMM2 reads done

  float ssum = 0.f, ssq = 0.f;
#pragma unroll
  for (int r = 0; r < 3; ++r) {
    int rowb = wave * 48 + r * 16 + kg * 4;
    f32x4 bs = *(const f32x4*)(b23 + rowb);
#pragma unroll
    for (int m = 0; m < 4; ++m) {
      int p = m * 16 + col;
      float v0 = gelu_f(acc[r][m][0] + bs[0]), v1 = gelu_f(acc[r][m][1] + bs[1]);
      float v2 = gelu_f(acc[r][m][2] + bs[2]), v3 = gelu_f(acc[r][m][3] + bs[3]);
      ssum += (v0 + v1) + (v2 + v3);
      ssq = fmaf(v0, v0, fmaf(v1, v1, fmaf(v2, v2, fmaf(v3, v3, ssq))));
      uint2 pk; pk.x = cvt_pk(v0, v1); pk.y = cvt_pk(v2, v3);
      *(uint2*)(B + lds_off(rowb >> 6, p, rowb & 63)) = pk;
    }
  }
  __syncthreads();                         // out tile visible
  store_tile(B, (char*)out + ((size_t)b * SPAT + p0) * 384, tid);
  stats_reduce(ssum, ssq, wave, lane, red, partials, blk);
}

// ---------------------------------------------------------------------------
// pass3: conv(w3e per-sample folded norm2)+b3e -> f32 channel-major d_out
// ---------------------------------------------------------------------------
__global__ __launch_bounds__(256, 4)
void pass3(const unsigned short* __restrict__ in, const unsigned short* __restrict__ w3e,
           const float* __restrict__ b3e, float* __restrict__ outf) {
  __shared__ __align__(16) char B[3 * 64 * 128];
  int blk = blockIdx.x, b = blk >> 9, p0 = (blk & 511) * 64;
  int tid = threadIdx.x, wave = tid >> 6, lane = tid & 63;
  int col = lane & 15, kg = lane >> 4;

  const char* ib = (const char*)in + (size_t)b * SPAT * 384;
  int G = tid & 7;
#pragma unroll
  for (int j = 0; j < 6; ++j) {
    const int c = j >> 1;
    int p = (j & 1) * 32 + (tid >> 3);
    s16x8 v = *(const s16x8*)(ib + (size_t)(p0 + p) * 384 + (c * 8 + G) * 16);
    *(s16x8*)(B + lds_off(c, p, G * 8)) = v;
  }
  __syncthreads();

  f32x4 acc[3][4] = {};
  do_gemm48<0>(B, w3e + (size_t)b * NCH * NCH, wave, col, kg, acc);

  const float* bb = b3e + b * NCH;
#pragma unroll
  for (int r = 0; r < 3; ++r) {
    int rowb = wave * 48 + r * 16 + kg * 4;
    f32x4 bs = *(const f32x4*)(bb + rowb);
#pragma unroll
    for (int m = 0; m < 4; ++m) {
      int p = p0 + m * 16 + col;
#pragma unroll
      for (int j = 0; j < 4; ++j)
        outf[((size_t)b * NCH + rowb + j) * SPAT + p] = acc[r][m][j] + bs[j];
    }
  }
}

// Deterministic stats finalize: 512 partials/sample -> f32 AC + bf16 ACbf
__global__ void stats_finalize(const float* __restrict__ partials,
                               const float* __restrict__ nw, const float* __restrict__ nb,
                               float* __restrict__ AC, unsigned short* __restrict__ ACbf) {
  int b = blockIdx.x, tid = threadIdx.x;
  __shared__ float s0[256], s1[256];
  float a = 0.f, c = 0.f;
  for (int i = tid; i < TILES_PER_B; i += 256) {
    a += partials[(b * TILES_PER_B + i) * 2];
    c += partials[(b * TILES_PER_B + i) * 2 + 1];
  }
  s0[tid] = a; s1[tid] = c;
  __syncthreads();
  for (int st = 128; st > 0; st >>= 1) {
    if (tid < st) { s0[tid] += s0[tid + st]; s1[tid] += s1[tid + st]; }
    __syncthreads();
  }
  float inv_n = 1.0f / (float)NELEM_PER_B;
  float mu = s0[0] * inv_n;
  float var = s1[0] * inv_n - mu * mu;
  float rs = rsqrtf(var + 1e-5f);
  if (tid < NCH) {
    float A = rs * nw[tid];
    float C = nb[tid] - mu * A;
    AC[b * 2 * NCH + tid] = A;
    AC[b * 2 * NCH + NCH + tid] = C;
    ACbf[b * 2 * NCH + tid] = f2bf(A);
    ACbf[b * 2 * NCH + NCH + tid] = f2bf(C);
  }
}

__global__ void prep_weights(const float* __restrict__ w1, const float* __restrict__ w21,
                             const float* __restrict__ w22, const float* __restrict__ w23,
                             unsigned short* __restrict__ wb) {
  int i = blockIdx.x * 256 + threadIdx.x;
  if (i >= 4 * NCH * NCH) return;
  int m = i / (NCH * NCH), r = i % (NCH * NCH);
  const float* src = (m == 0) ? w1 : (m == 1) ? w22 : (m == 2) ? w21 : w23;
  wb[i] = f2bf(src[r]);
}

// Parallel fold of norm2 into w3/b3: one 64-thread block per (b, o)
__global__ void prep_w3p(const float* __restrict__ w3, const float* __restrict__ b3,
                         const float* __restrict__ AC2,
                         unsigned short* __restrict__ w3e, float* __restrict__ b3e) {
  int gb = blockIdx.x;
  int b = gb / NCH, o = gb - b * NCH;
  const float* A = AC2 + b * 2 * NCH;
  const float* C = A + NCH;
  int lane = threadIdx.x;
  float s = 0.f;
#pragma unroll
  for (int k = 0; k < 3; ++k) {
    int c = k * 64 + lane;
    float w = w3[o * NCH + c];
    w3e[((size_t)b * NCH + o) * NCH + c] = f2bf(w * A[c]);
    s = fmaf(w, C[c], s);
  }
#pragma unroll
  for (int off = 1; off < 64; off <<= 1) s += __shfl_xor(s, off, 64);
  if (lane == 0) b3e[b * NCH + o] = b3[o] + s;
}

extern "C" void kernel_launch(void* const* d_in, const int* in_sizes, int n_in,
                              void* d_out, int out_size, void* d_ws, size_t ws_size,
                              hipStream_t stream) {
  const float* x   = (const float*)d_in[0];
  const float* w1  = (const float*)d_in[1];
  const float* b1  = (const float*)d_in[2];
  const float* n1w = (const float*)d_in[3];
  const float* n1b = (const float*)d_in[4];
  const float* w21 = (const float*)d_in[5];
  const float* b21 = (const float*)d_in[6];
  const float* w22 = (const float*)d_in[7];
  const float* b22 = (const float*)d_in[8];
  const float* w23 = (const float*)d_in[9];
  const float* b23 = (const float*)d_in[10];
  const float* n2w = (const float*)d_in[11];
  const float* n2b = (const float*)d_in[12];
  const float* w3  = (const float*)d_in[13];
  const float* b3  = (const float*)d_in[14];

  char* ws = (char*)d_ws;
  size_t off = 0;
  unsigned short* wb = (unsigned short*)(ws + off); off += (size_t)4 * NCH * NCH * 2;
  off = (off + 255) & ~(size_t)255;
  unsigned short* w3e = (unsigned short*)(ws + off); off += (size_t)NB * NCH * NCH * 2;
  off = (off + 255) & ~(size_t)255;
  float* b3e = (float*)(ws + off); off += NB * NCH * 4;
  float* AC1 = (float*)(ws + off); off += NB * 2 * NCH * 4;
  float* AC2 = (float*)(ws + off); off += NB * 2 * NCH * 4;
  unsigned short* ACbf1 = (unsigned short*)(ws + off); off += NB * 2 * NCH * 2;
  unsigned short* ACbf2 = (unsigned short*)(ws + off); off += NB * 2 * NCH * 2;
  off = (off + 255) & ~(size_t)255;
  float* part1 = (float*)(ws + off); off += (size_t)NBLK * 2 * 4;
  float* part2 = (float*)(ws + off); off += (size_t)NBLK * 2 * 4;
  off = (off + 255) & ~(size_t)255;
  unsigned short* R1 = (unsigned short*)(ws + off);   // 100.7 MB bf16 (ws)
  unsigned short* R2 = (unsigned short*)d_out;        // bf16 scratch in d_out

  prep_weights<<<(4 * NCH * NCH + 255) / 256, 256, 0, stream>>>(w1, w21, w22, w23, wb);

  // K1: x -> R1 (conv w1 + b1), stats1
  pass1<<<NBLK, 256, 0, stream>>>(x, wb + 0 * NCH * NCH, b1, R1, part1);
  stats_finalize<<<NB, 256, 0, stream>>>(part1, n1w, n1b, AC1, ACbf1);

  // K2a: norm1+gelu fused staging, H-shift, conv w22 + b22: R1 -> R2
  pass2a<<<NBLK, 256, 0, stream>>>(R1, wb + 1 * NCH * NCH, b22, R2, ACbf1);

  // K2bc: D-shift stage -> w21 -> T -> W-shift -> w23 + gelu + stats2: R2 -> R1
  pass2bc<<<NBLK, 256, 0, stream>>>(R2, wb + 2 * NCH * NCH, b21,
                                    wb + 3 * NCH * NCH, b23, R1, part2);
  stats_finalize<<<NB, 256, 0, stream>>>(part2, n2w, n2b, AC2, ACbf2);
  prep_w3p<<<NB * NCH, 64, 0, stream>>>(w3, b3, AC2, w3e, b3e);

  // K3: folded norm2 + conv w3: R1 -> d_out (f32 channel-major)
  pass3<<<NBLK, 256, 0, stream>>>(R1, w3e, b3e, (float*)d_out);
}

// Round 16
// 313.302 us; speedup vs baseline: 1.1007x; 1.0228x over previous
//
#include <hip/hip_runtime.h>
#include <math.h>

#define NCH 192
#define NB 8
#define SPAT 32768                        // 32^3
#define TILES_PER_B 512                   // 64-pos tiles per sample
#define NBLK (NB * TILES_PER_B)           // 4096 blocks per pass
#define NELEM_PER_B ((size_t)NCH * SPAT)  // 6291456

typedef short s16x8 __attribute__((ext_vector_type(8)));
typedef float f32x4 __attribute__((ext_vector_type(4)));

__device__ __forceinline__ float bf2f(unsigned short h) {
  return __uint_as_float(((unsigned)h) << 16);
}
__device__ __forceinline__ unsigned short f2bf(float f) {
  unsigned u = __float_as_uint(f);
  u += 0x7FFF + ((u >> 16) & 1);
  return (unsigned short)(u >> 16);
}
// packed RNE f32->bf16 pair in ONE instruction
__device__ __forceinline__ unsigned cvt_pk(float lo, float hi) {
  unsigned r;
  asm("v_cvt_pk_bf16_f32 %0, %1, %2" : "=v"(r) : "v"(lo), "v"(hi));
  return r;
}

// tanh-form GELU (max abs err ~5e-4; budget 9.1e-2).  ~8 VALU ops.
__device__ __forceinline__ float gelu_f(float x) {
  float x2 = x * x;
  float z2 = x * fmaf(x2, 0.0713548163f, 1.5957769100f);
  float e = __expf(z2);
  float r = __builtin_amdgcn_rcpf(e + 1.0f);
  return fmaf(-r, x, x);
}

// reflect-shift of axis index i by chunk c (shift s = c-1): -1->1, 32->30
__device__ __forceinline__ int rshift(int i, int c) {
  int j = i - (c - 1);
  j = (j < 0) ? 1 : j;
  j = (j > 31) ? 30 : j;
  return j;
}

// LDS tile [c:3][p:64][u:64] bf16 (128B rows); 16B-granule XOR swizzle
// granule' = (u>>3) ^ (p&7) ^ ((p>>3)&7).  SINGLE helper everywhere (rule #21).
__device__ __forceinline__ int lds_off(int c, int p, int u) {
  return (c * 64 + p) * 128 + 16 * (((u >> 3) ^ (p & 7) ^ ((p >> 3) & 7)) & 7) + 2 * (u & 7);
}

// 48-out-ch-per-wave x 64-pos GEMM with 2-deep pipelined weight fragments.
template <int SHIFTW>
__device__ __forceinline__ void do_gemm48(const char* __restrict__ B,
                                          const unsigned short* __restrict__ wm,
                                          int wave, int col, int kg,
                                          f32x4 acc[3][4]) {
  const unsigned short* wp = wm + (wave * 48 + col) * NCH + kg * 8;
  s16x8 afc[3], afn[3];
#pragma unroll
  for (int r = 0; r < 3; ++r) afc[r] = *(const s16x8*)(wp + r * 16 * NCH);
#pragma unroll
  for (int ks = 0; ks < 6; ++ks) {
    if (ks < 5) {
#pragma unroll
      for (int r = 0; r < 3; ++r)
        afn[r] = *(const s16x8*)(wp + (ks + 1) * 32 + r * 16 * NCH);
    }
    int k0 = ks * 32 + kg * 8;
    int c = k0 >> 6, u = k0 & 63;
    s16x8 bf[4];
#pragma unroll
    for (int m = 0; m < 4; ++m) {
      int p = m * 16 + col;
      int ps = SHIFTW ? ((p & 32) | rshift(p & 31, c)) : p;
      bf[m] = *(const s16x8*)(B + lds_off(c, ps, u));
    }
#pragma unroll
    for (int r = 0; r < 3; ++r)
#pragma unroll
      for (int m = 0; m < 4; ++m)
        acc[r][m] = __builtin_amdgcn_mfma_f32_16x16x32_bf16(afc[r], bf[m], acc[r][m], 0, 0, 0);
#pragma unroll
    for (int r = 0; r < 3; ++r) afc[r] = afn[r];
  }
}

// block (4-wave) stats reduce -> partials[blk]
__device__ __forceinline__ void stats_reduce(float ssum, float ssq, int wave, int lane,
                                             float* red, float* partials, int blk) {
#pragma unroll
  for (int off = 1; off < 64; off <<= 1) {
    ssum += __shfl_xor(ssum, off, 64);
    ssq += __shfl_xor(ssq, off, 64);
  }
  if (lane == 0) { red[wave * 2] = ssum; red[wave * 2 + 1] = ssq; }
  __syncthreads();
  if (wave == 0 && lane == 0) {
    partials[blk * 2] = red[0] + red[2] + red[4] + red[6];
    partials[blk * 2 + 1] = red[1] + red[3] + red[5] + red[7];
  }
}

// In-block stats finalize: every block reduces its sample's 512 partial pairs
// (4KB, L2-broadcast) -> acs[0..191]=A, acs[192..383]=C.  Ends with a barrier
// that also covers acs visibility.  ~1 f32x4 load + shuffle tree per thread.
__device__ __forceinline__ void stats_inline(const float* __restrict__ partials, int b,
                                             const float* __restrict__ nw,
                                             const float* __restrict__ nb,
                                             float* __restrict__ acs, float* __restrict__ red,
                                             int tid, int wave, int lane) {
  f32x4 v = *(const f32x4*)(partials + ((size_t)b * TILES_PER_B + 2 * tid) * 2);
  float a = v[0] + v[2], c = v[1] + v[3];
#pragma unroll
  for (int off = 1; off < 64; off <<= 1) {
    a += __shfl_xor(a, off, 64);
    c += __shfl_xor(c, off, 64);
  }
  if (lane == 0) { red[wave * 2] = a; red[wave * 2 + 1] = c; }
  __syncthreads();
  float sum = red[0] + red[2] + red[4] + red[6];
  float sq = red[1] + red[3] + red[5] + red[7];
  float inv_n = 1.0f / (float)NELEM_PER_B;
  float mu = sum * inv_n;
  float var = sq * inv_n - mu * mu;
  float rs = rsqrtf(var + 1e-5f);
  if (tid < NCH) {
    float A = rs * nw[tid];
    acs[tid] = A;
    acs[NCH + tid] = nb[tid] - mu * A;
  }
  __syncthreads();   // acs visible
}

// coop store: LDS tile -> bf16 [p][c] global (contiguous 24KB)
__device__ __forceinline__ void store_tile(const char* __restrict__ L, char* __restrict__ ob,
                                           int tid) {
  int G = tid & 7;
#pragma unroll
  for (int j = 0; j < 6; ++j) {
    const int c = j >> 1;
    int p = (j & 1) * 32 + (tid >> 3);
    s16x8 v = *(const s16x8*)(L + lds_off(c, p, G * 8));
    *(s16x8*)(ob + (size_t)p * 384 + (c * 8 + G) * 16) = v;
  }
}

// ---------------------------------------------------------------------------
// pass1: x (f32 ch-major) -> conv(w1)+b1 -> bf16 [p][c], stats1
// ---------------------------------------------------------------------------
__global__ __launch_bounds__(256, 4)
void pass1(const float* __restrict__ x, const unsigned short* __restrict__ w1b,
           const float* __restrict__ b1, unsigned short* __restrict__ out,
           float* __restrict__ partials) {
  __shared__ __align__(16) char B[3 * 64 * 128];
  __shared__ float red[8];
  int blk = blockIdx.x, b = blk >> 9, p0 = (blk & 511) * 64;
  int tid = threadIdx.x, wave = tid >> 6, lane = tid & 63;
  int col = lane & 15, kg = lane >> 4;

  // stage: f32 transpose-gather of ch-pairs, packed b32 writes
  const float* xb = x + (size_t)b * NELEM_PER_B + p0;
  int q = tid & 15;
#pragma unroll
  for (int j = 0; j < 6; ++j) {
    int chp = j * 16 + (tid >> 4);          // ch-pair 0..95
    int ch0 = 2 * chp;
    int cc = chp >> 5, u0 = ch0 & 63;
    const float* s0 = xb + (size_t)ch0 * SPAT + 4 * q;
    f32x4 a = *(const f32x4*)s0;
    f32x4 c2 = *(const f32x4*)(s0 + SPAT);
#pragma unroll
    for (int i = 0; i < 4; ++i)
      *(unsigned*)(B + lds_off(cc, 4 * q + i, u0)) = cvt_pk(a[i], c2[i]);
  }
  __syncthreads();

  f32x4 acc[3][4] = {};
  do_gemm48<0>(B, w1b, wave, col, kg, acc);

  float ssum = 0.f, ssq = 0.f;
  __syncthreads();   // all B reads done; reuse as output tile
#pragma unroll
  for (int r = 0; r < 3; ++r) {
    int rowb = wave * 48 + r * 16 + kg * 4;
    f32x4 bs = *(const f32x4*)(b1 + rowb);
#pragma unroll
    for (int m = 0; m < 4; ++m) {
      int p = m * 16 + col;
      float v0 = acc[r][m][0] + bs[0], v1 = acc[r][m][1] + bs[1];
      float v2 = acc[r][m][2] + bs[2], v3 = acc[r][m][3] + bs[3];
      ssum += (v0 + v1) + (v2 + v3);
      ssq = fmaf(v0, v0, fmaf(v1, v1, fmaf(v2, v2, fmaf(v3, v3, ssq))));
      uint2 pk; pk.x = cvt_pk(v0, v1); pk.y = cvt_pk(v2, v3);
      *(uint2*)(B + lds_off(rowb >> 6, p, rowb & 63)) = pk;
    }
  }
  __syncthreads();
  store_tile(B, (char*)out + ((size_t)b * SPAT + p0) * 384, tid);
  stats_reduce(ssum, ssq, wave, lane, red, partials, blk);
}

// ---------------------------------------------------------------------------
// pass2a: in-block stats1 finalize -> H-shift gather + fused norm1+GELU,
//         conv(w22)+b22 -> bf16 [p][c]
// ---------------------------------------------------------------------------
__global__ __launch_bounds__(256, 4)
void pass2a(const unsigned short* __restrict__ in, const unsigned short* __restrict__ w22b,
            const float* __restrict__ b22, unsigned short* __restrict__ out,
            const float* __restrict__ part1,
            const float* __restrict__ n1w, const float* __restrict__ n1b) {
  __shared__ __align__(16) char B[3 * 64 * 128];
  __shared__ __align__(16) float acs[2 * NCH];
  __shared__ float red[8];
  int blk = blockIdx.x, b = blk >> 9, p0 = (blk & 511) * 64;
  int tid = threadIdx.x, wave = tid >> 6, lane = tid & 63;
  int col = lane & 15, kg = lane >> 4;

  stats_inline(part1, b, n1w, n1b, acs, red, tid, wave, lane);

  const char* ib = (const char*)in + (size_t)b * SPAT * 384;
  int G = tid & 7;
#pragma unroll
  for (int j = 0; j < 6; ++j) {
    const int c = j >> 1;
    int p = (j & 1) * 32 + (tid >> 3);
    int h = ((p0 + p) >> 5) & 31;
    int sp = (p0 + p) + (rshift(h, c) - h) * 32;
    s16x8 v = *(const s16x8*)(ib + (size_t)sp * 384 + (c * 8 + G) * 16);
    int ch0 = c * 64 + G * 8;
    f32x4 a0 = *(const f32x4*)(acs + ch0), a1 = *(const f32x4*)(acs + ch0 + 4);
    f32x4 c0 = *(const f32x4*)(acs + NCH + ch0), c1 = *(const f32x4*)(acs + NCH + ch0 + 4);
    unsigned w[4];
#pragma unroll
    for (int i = 0; i < 4; ++i) {
      float A0 = (i < 2) ? a0[2 * i] : a1[2 * i - 4];
      float A1 = (i < 2) ? a0[2 * i + 1] : a1[2 * i - 3];
      float C0 = (i < 2) ? c0[2 * i] : c1[2 * i - 4];
      float C1 = (i < 2) ? c0[2 * i + 1] : c1[2 * i - 3];
      float f0 = gelu_f(fmaf(bf2f((unsigned short)v[2 * i]), A0, C0));
      float f1 = gelu_f(fmaf(bf2f((unsigned short)v[2 * i + 1]), A1, C1));
      w[i] = cvt_pk(f0, f1);
    }
    *(uint2*)(B + lds_off(c, p, G * 8)) = make_uint2(w[0], w[1]);
    *(uint2*)(B + lds_off(c, p, G * 8 + 4)) = make_uint2(w[2], w[3]);
  }
  __syncthreads();

  f32x4 acc[3][4] = {};
  do_gemm48<0>(B, w22b, wave, col, kg, acc);
  __syncthreads();
#pragma unroll
  for (int r = 0; r < 3; ++r) {
    int rowb = wave * 48 + r * 16 + kg * 4;
    f32x4 bs = *(const f32x4*)(b22 + rowb);
#pragma unroll
    for (int m = 0; m < 4; ++m) {
      int p = m * 16 + col;
      uint2 pk;
      pk.x = cvt_pk(acc[r][m][0] + bs[0], acc[r][m][1] + bs[1]);
      pk.y = cvt_pk(acc[r][m][2] + bs[2], acc[r][m][3] + bs[3]);
      *(uint2*)(B + lds_off(rowb >> 6, p, rowb & 63)) = pk;
    }
  }
  __syncthreads();
  store_tile(B, (char*)out + ((size_t)b * SPAT + p0) * 384, tid);
}

// ---------------------------------------------------------------------------
// pass2bc: D-shift gather -> conv(w21)+b21 -> T (in-place LDS) -> W-shift
//          read -> conv(w23)+b23 -> GELU -> stats2 -> bf16 [p][c]
// ---------------------------------------------------------------------------
__global__ __launch_bounds__(256, 4)
void pass2bc(const unsigned short* __restrict__ in, const unsigned short* __restrict__ w21b,
             const float* __restrict__ b21, const unsigned short* __restrict__ w23b,
             const float* __restrict__ b23, unsigned short* __restrict__ out,
             float* __restrict__ partials) {
  __shared__ __align__(16) char B[3 * 64 * 128];
  __shared__ float red[8];
  int blk = blockIdx.x, b = blk >> 9, p0 = (blk & 511) * 64;
  int tid = threadIdx.x, wave = tid >> 6, lane = tid & 63;
  int col = lane & 15, kg = lane >> 4;

  int d = p0 >> 10;
  int soff[3];
#pragma unroll
  for (int c = 0; c < 3; ++c) soff[c] = (rshift(d, c) - d) * 1024;

  const char* ib = (const char*)in + (size_t)b * SPAT * 384;
  int G = tid & 7;
#pragma unroll
  for (int j = 0; j < 6; ++j) {
    const int c = j >> 1;
    int p = (j & 1) * 32 + (tid >> 3);
    s16x8 v = *(const s16x8*)(ib + (size_t)(p0 + p + soff[c]) * 384 + (c * 8 + G) * 16);
    *(s16x8*)(B + lds_off(c, p, G * 8)) = v;
  }
  __syncthreads();                         // B visible

  f32x4 acc[3][4] = {};
  do_gemm48<0>(B, w21b, wave, col, kg, acc);
  __syncthreads();                         // GEMM1 reads done
#pragma unroll
  for (int r = 0; r < 3; ++r) {
    int rowb = wave * 48 + r * 16 + kg * 4;
    f32x4 bs = *(const f32x4*)(b21 + rowb);
#pragma unroll
    for (int m = 0; m < 4; ++m) {
      int p = m * 16 + col;
      uint2 pk;
      pk.x = cvt_pk(acc[r][m][0] + bs[0], acc[r][m][1] + bs[1]);
      pk.y = cvt_pk(acc[r][m][2] + bs[2], acc[r][m][3] + bs[3]);
      *(uint2*)(B + lds_off(rowb >> 6, p, rowb & 63)) = pk;
    }
  }
  __syncthreads();                         // T visible

#pragma unroll
  for (int r = 0; r < 3; ++r)
#pragma unroll
    for (int m = 0; m < 4; ++m) acc[r][m] = (f32x4){0.f, 0.f, 0.f, 0.f};
  do_gemm48<1>(B, w23b, wave, col, kg, acc);   // W-shift at read
  __syncthreads();                         // GEMM2 reads done

  float ssum = 0.f, ssq = 0.f;
#pragma unroll
  for (int r = 0; r < 3; ++r) {
    int rowb = wave * 48 + r * 16 + kg * 4;
    f32x4 bs = *(const f32x4*)(b23 + rowb);
#pragma unroll
    for (int m = 0; m < 4; ++m) {
      int p = m * 16 + col;
      float v0 = gelu_f(acc[r][m][0] + bs[0]), v1 = gelu_f(acc[r][m][1] + bs[1]);
      float v2 = gelu_f(acc[r][m][2] + bs[2]), v3 = gelu_f(acc[r][m][3] + bs[3]);
      ssum += (v0 + v1) + (v2 + v3);
      ssq = fmaf(v0, v0, fmaf(v1, v1, fmaf(v2, v2, fmaf(v3, v3, ssq))));
      uint2 pk; pk.x = cvt_pk(v0, v1); pk.y = cvt_pk(v2, v3);
      *(uint2*)(B + lds_off(rowb >> 6, p, rowb & 63)) = pk;
    }
  }
  __syncthreads();                         // out tile visible
  store_tile(B, (char*)out + ((size_t)b * SPAT + p0) * 384, tid);
  stats_reduce(ssum, ssq, wave, lane, red, partials, blk);
}

// ---------------------------------------------------------------------------
// pass3: in-block stats2 finalize -> affine staging (norm2 applied to
// ACTIVATIONS: v' = h*A2+C2) -> conv(w3)+b3 -> f32 channel-major d_out.
// Exact: sum_c w3[o][c]*(h*A2[c]+C2[c]) + b3[o] == folded-norm2 conv.
// ---------------------------------------------------------------------------
__global__ __launch_bounds__(256, 4)
void pass3(const unsigned short* __restrict__ in, const unsigned short* __restrict__ w3b,
           const float* __restrict__ b3, float* __restrict__ outf,
           const float* __restrict__ part2,
           const float* __restrict__ n2w, const float* __restrict__ n2b) {
  __shared__ __align__(16) char B[3 * 64 * 128];
  __shared__ __align__(16) float acs[2 * NCH];
  __shared__ float red[8];
  int blk = blockIdx.x, b = blk >> 9, p0 = (blk & 511) * 64;
  int tid = threadIdx.x, wave = tid >> 6, lane = tid & 63;
  int col = lane & 15, kg = lane >> 4;

  stats_inline(part2, b, n2w, n2b, acs, red, tid, wave, lane);

  const char* ib = (const char*)in + (size_t)b * SPAT * 384;
  int G = tid & 7;
#pragma unroll
  for (int j = 0; j < 6; ++j) {
    const int c = j >> 1;
    int p = (j & 1) * 32 + (tid >> 3);
    s16x8 v = *(const s16x8*)(ib + (size_t)(p0 + p) * 384 + (c * 8 + G) * 16);
    int ch0 = c * 64 + G * 8;
    f32x4 a0 = *(const f32x4*)(acs + ch0), a1 = *(const f32x4*)(acs + ch0 + 4);
    f32x4 c0 = *(const f32x4*)(acs + NCH + ch0), c1 = *(const f32x4*)(acs + NCH + ch0 + 4);
    unsigned w[4];
#pragma unroll
    for (int i = 0; i < 4; ++i) {
      float A0 = (i < 2) ? a0[2 * i] : a1[2 * i - 4];
      float A1 = (i < 2) ? a0[2 * i + 1] : a1[2 * i - 3];
      float C0 = (i < 2) ? c0[2 * i] : c1[2 * i - 4];
      float C1 = (i < 2) ? c0[2 * i + 1] : c1[2 * i - 3];
      float f0 = fmaf(bf2f((unsigned short)v[2 * i]), A0, C0);
      float f1 = fmaf(bf2f((unsigned short)v[2 * i + 1]), A1, C1);
      w[i] = cvt_pk(f0, f1);
    }
    *(uint2*)(B + lds_off(c, p, G * 8)) = make_uint2(w[0], w[1]);
    *(uint2*)(B + lds_off(c, p, G * 8 + 4)) = make_uint2(w[2], w[3]);
  }
  __syncthreads();

  f32x4 acc[3][4] = {};
  do_gemm48<0>(B, w3b, wave, col, kg, acc);

#pragma unroll
  for (int r = 0; r < 3; ++r) {
    int rowb = wave * 48 + r * 16 + kg * 4;
    f32x4 bs = *(const f32x4*)(b3 + rowb);
#pragma unroll
    for (int m = 0; m < 4; ++m) {
      int p = p0 + m * 16 + col;
#pragma unroll
      for (int j = 0; j < 4; ++j)
        outf[((size_t)b * NCH + rowb + j) * SPAT + p] = acc[r][m][j] + bs[j];
    }
  }
}

// fp32 -> bf16 weight conversion: slots 0=w1, 1=w22, 2=w21, 3=w23, 4=w3
__global__ void prep_weights(const float* __restrict__ w1, const float* __restrict__ w21,
                             const float* __restrict__ w22, const float* __restrict__ w23,
                             const float* __restrict__ w3,
                             unsigned short* __restrict__ wb) {
  int i = blockIdx.x * 256 + threadIdx.x;
  if (i >= 5 * NCH * NCH) return;
  int m = i / (NCH * NCH), r = i % (NCH * NCH);
  const float* src = (m == 0) ? w1 : (m == 1) ? w22 : (m == 2) ? w21 : (m == 3) ? w23 : w3;
  wb[i] = f2bf(src[r]);
}

extern "C" void kernel_launch(void* const* d_in, const int* in_sizes, int n_in,
                              void* d_out, int out_size, void* d_ws, size_t ws_size,
                              hipStream_t stream) {
  const float* x   = (const float*)d_in[0];
  const float* w1  = (const float*)d_in[1];
  const float* b1  = (const float*)d_in[2];
  const float* n1w = (const float*)d_in[3];
  const float* n1b = (const float*)d_in[4];
  const float* w21 = (const float*)d_in[5];
  const float* b21 = (const float*)d_in[6];
  const float* w22 = (const float*)d_in[7];
  const float* b22 = (const float*)d_in[8];
  const float* w23 = (const float*)d_in[9];
  const float* b23 = (const float*)d_in[10];
  const float* n2w = (const float*)d_in[11];
  const float* n2b = (const float*)d_in[12];
  const float* w3  = (const float*)d_in[13];
  const float* b3  = (const float*)d_in[14];

  char* ws = (char*)d_ws;
  size_t off = 0;
  unsigned short* wb = (unsigned short*)(ws + off); off += (size_t)5 * NCH * NCH * 2;
  off = (off + 255) & ~(size_t)255;
  float* part1 = (float*)(ws + off); off += (size_t)NBLK * 2 * 4;
  float* part2 = (float*)(ws + off); off += (size_t)NBLK * 2 * 4;
  off = (off + 255) & ~(size_t)255;
  unsigned short* R1 = (unsigned short*)(ws + off);   // 100.7 MB bf16 (ws)
  unsigned short* R2 = (unsigned short*)d_out;        // bf16 scratch in d_out

  prep_weights<<<(5 * NCH * NCH + 255) / 256, 256, 0, stream>>>(w1, w21, w22, w23, w3, wb);

  // K1: x -> R1 (conv w1 + b1), stats1
  pass1<<<NBLK, 256, 0, stream>>>(x, wb + 0 * NCH * NCH, b1, R1, part1);

  // K2a: in-block stats1 -> norm1+gelu fused staging, H-shift, conv w22: R1 -> R2
  pass2a<<<NBLK, 256, 0, stream>>>(R1, wb + 1 * NCH * NCH, b22, R2, part1, n1w, n1b);

  // K2bc: D-shift stage -> w21 -> T -> W-shift -> w23 + gelu + stats2: R2 -> R1
  pass2bc<<<NBLK, 256, 0, stream>>>(R2, wb + 2 * NCH * NCH, b21,
                                    wb + 3 * NCH * NCH, b23, R1, part2);

  // K3: in-block stats2 -> affine staging (norm2 on activations), conv w3: R1 -> d_out
  pass3<<<NBLK, 256, 0, stream>>>(R1, wb + 4 * NCH * NCH, b3, (float*)d_out,
                                  part2, n2w, n2b);
}